// Round 1
// baseline (560.854 us; speedup 1.0000x reference)
//
#include <hip/hip_runtime.h>

#define N_ROWS 100000
#define IN_F 64
#define OUT_F 16
#define KB 11            // number of basis functions (gs + so)
#define SLOTS 216        // per-feature partial: 38 band + 2 pad + 176 AtB (16B-aligned AtB)
#define PB (IN_F * SLOTS)   // 13824 floats per block-partial
#define CHUNK_ROWS 16
#define NCHUNKS (N_ROWS / CHUNK_ROWS)  // 6250 exactly
#define RGROUPS 16
#define MAX_NB 512

// ---------------------------------------------------------------------------
// Kernel 1: per-block partial AtA (banded, symmetric) and AtB accumulation.
// Block = 256 threads. thread t: feature i = t>>2, q = t&3, outputs o = 4q..4q+3.
// LDS stages the dense 11(+1 pad) basis values per (row, feature).
// ---------------------------------------------------------------------------
__global__ __launch_bounds__(256) void kan_partial(const float* __restrict__ x,
                                                   const float* __restrict__ y,
                                                   float* __restrict__ ws) {
    __shared__ float k_lds[CHUNK_ROWS * IN_F * 12];  // 48 KiB, stride 12 => 8-way max conflict
    const int tid = threadIdx.x;
    const int i4  = tid >> 2;
    const int q   = tid & 3;
    const int o4  = q * 4;

    float4 atb[KB];
    float  atA[KB];
#pragma unroll
    for (int kk = 0; kk < KB; ++kk) {
        atb[kk] = make_float4(0.f, 0.f, 0.f, 0.f);
        atA[kk] = 0.f;
    }

    for (int ch = blockIdx.x; ch < NCHUNKS; ch += gridDim.x) {
        const int n0 = ch * CHUNK_ROWS;
        // ---- phase 1: basis -> LDS (uniform cubic B-spline closed form) ----
#pragma unroll
        for (int s = 0; s < 4; ++s) {
            const int pp = tid + s * 256;          // pp = r*64 + i
            const float xv = x[n0 * IN_F + pp];    // fully coalesced
            float tpos = (xv + 1.0f) * 4.0f;       // cell coordinate in [0,8)
            int c = (int)floorf(tpos);
            c = c < 0 ? 0 : (c > 7 ? 7 : c);
            const float u   = tpos - (float)c;
            const float omu = 1.0f - u;
            const float b0 = omu * omu * omu * (1.0f / 6.0f);
            const float b3 = u * u * u * (1.0f / 6.0f);
            const float b1 = (0.5f * u - 1.0f) * u * u + (2.0f / 3.0f);
            const float b2 = 1.0f - b0 - b1 - b3;  // partition of unity (exact)
            float* kp = &k_lds[pp * 12];
            const float4 z = make_float4(0.f, 0.f, 0.f, 0.f);
            ((float4*)kp)[0] = z; ((float4*)kp)[1] = z; ((float4*)kp)[2] = z;
            kp[c] = b0; kp[c + 1] = b1; kp[c + 2] = b2; kp[c + 3] = b3;
        }
        __syncthreads();

        // ---- phase 2: accumulate AtB (dense over 11) and banded AtA ----
        const size_t ybase = (size_t)n0 * (IN_F * OUT_F) + (size_t)i4 * OUT_F + o4;
#pragma unroll 4
        for (int r = 0; r < CHUNK_ROWS; ++r) {
            const float* kp = &k_lds[(r * IN_F + i4) * 12];
            const float4 k0 = ((const float4*)kp)[0];
            const float4 k1 = ((const float4*)kp)[1];
            const float4 k2 = ((const float4*)kp)[2];
            const float k[12] = {k0.x, k0.y, k0.z, k0.w, k1.x, k1.y, k1.z, k1.w,
                                 k2.x, k2.y, k2.z, k2.w};
            const float4 y4 = *(const float4*)(y + ybase + (size_t)r * (IN_F * OUT_F));
#pragma unroll
            for (int kk = 0; kk < KB; ++kk) {
                atb[kk].x += k[kk] * y4.x;
                atb[kk].y += k[kk] * y4.y;
                atb[kk].z += k[kk] * y4.z;
                atb[kk].w += k[kk] * y4.w;
            }
            // banded symmetric AtA: thread q owns diagonal d = q (entries k[a]*k[a+q])
            if (q == 0) {
#pragma unroll
                for (int a = 0; a < 11; ++a) atA[a] += k[a] * k[a];
            } else if (q == 1) {
#pragma unroll
                for (int a = 0; a < 10; ++a) atA[a] += k[a] * k[a + 1];
            } else if (q == 2) {
#pragma unroll
                for (int a = 0; a < 9; ++a) atA[a] += k[a] * k[a + 2];
            } else {
#pragma unroll
                for (int a = 0; a < 8; ++a) atA[a] += k[a] * k[a + 3];
            }
        }
        __syncthreads();
    }

    // ---- epilogue: plain stores of the block partial ----
    float* base = ws + ((size_t)blockIdx.x * IN_F + i4) * SLOTS;
    const int bandBase = (q == 0) ? 0 : (q == 1) ? 11 : (q == 2) ? 21 : 30;
    const int bandCnt  = 11 - q;
    for (int m = 0; m < bandCnt; ++m) base[bandBase + m] = atA[m];
#pragma unroll
    for (int kk = 0; kk < KB; ++kk)
        *(float4*)(base + 40 + kk * 16 + o4) = atb[kk];
}

// ---------------------------------------------------------------------------
// Kernel 2: tree-reduce nb partials -> RGROUPS partials (coalesced).
// ---------------------------------------------------------------------------
__global__ __launch_bounds__(256) void kan_reduce(float* __restrict__ ws, int nb) {
    const int gid = blockIdx.x * 256 + threadIdx.x;  // grid sized exactly RGROUPS*PB
    const int e = gid % PB;
    const int g = gid / PB;
    float val = 0.f;
#pragma unroll 4
    for (int p = g; p < nb; p += RGROUPS) val += ws[(size_t)p * PB + e];
    ws[((size_t)nb + g) * PB + e] = val;
}

// ---------------------------------------------------------------------------
// Kernel 3: one block per feature. Sum RGROUPS partials, build augmented
// [AtA | AtB] (11 x 27) in LDS, Gauss-Jordan (SPD, no pivoting), write out
// in [out, in, K] order.
// ---------------------------------------------------------------------------
__global__ __launch_bounds__(320) void kan_solve(const float* __restrict__ ws2,
                                                 float* __restrict__ out) {
    __shared__ float M[11][28];
    const int i = blockIdx.x;
    const int tid = threadIdx.x;

    float val = 0.f;
    if (tid < SLOTS) {
#pragma unroll
        for (int g = 0; g < RGROUPS; ++g)
            val += ws2[(size_t)g * PB + (size_t)i * SLOTS + tid];
    }
    {   // zero the matrix region
        const int r = tid / 28, c = tid % 28;
        if (r < 11) M[r][c] = 0.f;
    }
    __syncthreads();
    if (tid < 38) {  // banded symmetric AtA
        int d, a;
        if (tid < 11)      { d = 0; a = tid; }
        else if (tid < 21) { d = 1; a = tid - 11; }
        else if (tid < 30) { d = 2; a = tid - 21; }
        else               { d = 3; a = tid - 30; }
        M[a][a + d] = val;
        M[a + d][a] = val;
    } else if (tid >= 40 && tid < SLOTS) {  // AtB
        const int e = tid - 40;
        M[e >> 4][11 + (e & 15)] = val;
    }
    __syncthreads();

    const int rr = tid / 28, cc = tid % 28;
    const bool active = (rr < 11) && (cc < 27);
    for (int p = 0; p < 11; ++p) {
        float pd = 1.f, mpc = 0.f, mrp = 0.f, mrc = 0.f;
        if (active) { pd = M[p][p]; mpc = M[p][cc]; mrp = M[rr][p]; mrc = M[rr][cc]; }
        __syncthreads();
        if (active) {
            const float s = mpc / pd;
            M[rr][cc] = (rr == p) ? s : mrc - mrp * s;
        }
        __syncthreads();
    }

    if (tid < 176) {
        const int o = tid / 11, r2 = tid % 11;
        out[o * (IN_F * KB) + i * KB + r2] = M[r2][11 + o];
    }
}

extern "C" void kernel_launch(void* const* d_in, const int* in_sizes, int n_in,
                              void* d_out, int out_size, void* d_ws, size_t ws_size,
                              hipStream_t stream) {
    const float* x = (const float*)d_in[0];
    const float* y = (const float*)d_in[1];
    // d_in[2] = grid: uniform by construction; closed form hardcoded.
    float* out = (float*)d_out;
    float* ws  = (float*)d_ws;

    const size_t per_block = (size_t)PB * sizeof(float);  // 55296 B
    long cap = (long)(ws_size / per_block) - RGROUPS;
    int nb = (int)(cap < 1 ? 1 : (cap > MAX_NB ? MAX_NB : cap));
    if (nb > NCHUNKS) nb = NCHUNKS;

    kan_partial<<<nb, 256, 0, stream>>>(x, y, ws);
    kan_reduce<<<(RGROUPS * PB) / 256, 256, 0, stream>>>(ws, nb);
    kan_solve<<<IN_F, 320, 0, stream>>>(ws + (size_t)nb * PB, out);
}